// Round 8
// baseline (94.149 us; speedup 1.0000x reference)
//
#include <hip/hip_runtime.h>
#include <math.h>

// x: [128,128,128,16] f32 ; MaxPool3d win 4 stride 2 -> pooled [63,63,63,16]
// patches: 30^3 cubes of 4^3 at stride 2 -> out (27000, 64, 16) f32
#define D0 128
#define NC 16
#define DP 63
#define NPATCH 30
#define DCH 2                        // dp outputs per thread
#define NCHUNK 32                    // ceil(63/2); last chunk emits 1 output
#define POOL_THREADS (NCHUNK*DP*DP*4)             // thread per (chunk,hp,wp,c4)
#define OUT_THREADS  (NPATCH*NPATCH*NPATCH*64*4)  // thread per out float4

typedef float f32x4 __attribute__((ext_vector_type(4)));  // native vec for NT store

__device__ __forceinline__ float4 f4max(float4 a, float4 b) {
    return make_float4(fmaxf(a.x, b.x), fmaxf(a.y, b.y), fmaxf(a.z, b.z), fmaxf(a.w, b.w));
}

// max over the 4x4 (h,w) window of d-row `r` for channel quad c4
__device__ __forceinline__ float4 hwmax(const float* __restrict__ x, int r, int hwbase, int c4) {
    const size_t dbase = (size_t)r * D0 * D0 + hwbase;
    float4 m = make_float4(-INFINITY, -INFINITY, -INFINITY, -INFINITY);
#pragma unroll
    for (int v = 0; v < 4; ++v) {
#pragma unroll
        for (int w = 0; w < 4; ++w) {
            const float4 val = *reinterpret_cast<const float4*>(
                &x[(dbase + v * D0 + w) * NC + c4 * 4]);
            m = f4max(m, val);
        }
    }
    return m;
}

// Rolling-d pool, DCH=2: 508k threads (~31 waves/CU) for latency hiding,
// 6 rows / 4-row stride = 1.5x worst-case d-refetch (adjacent chunks are
// co-resident -> boundary rows mostly L2-absorbed).
__global__ void pool_kernel(const float* __restrict__ x, float* __restrict__ pooled) {
    const int tid = blockIdx.x * blockDim.x + threadIdx.x;
    if (tid >= POOL_THREADS) return;
    const int c4 = tid & 3;
    int rest = tid >> 2;
    const int wp = rest % DP; rest /= DP;
    const int hp = rest % DP;
    const int chunk = rest / DP;       // 0..31 (wave-uniform)
    const int dp0 = chunk * DCH;
    const int r0 = chunk * 4;          // first input d-row
    const int hwbase = (hp * 2) * D0 + wp * 2;

    float4 row0 = hwmax(x, r0 + 0, hwbase, c4);
    float4 row1 = hwmax(x, r0 + 1, hwbase, c4);
    float4 row2 = hwmax(x, r0 + 2, hwbase, c4);
    float4 row3 = hwmax(x, r0 + 3, hwbase, c4);

    const float4 o0 = f4max(f4max(row0, row1), f4max(row2, row3));
    // store lanes (c4 fastest, wp next) -> contiguous per-wave store
    *reinterpret_cast<float4*>(&pooled[(size_t)(((dp0 * DP + hp) * DP + wp) * 4 + c4) * 4]) = o0;

    if (chunk < NCHUNK - 1) {          // wave-uniform branch; dp0+1 <= 62
        float4 row4 = hwmax(x, r0 + 4, hwbase, c4);
        float4 row5 = hwmax(x, r0 + 5, hwbase, c4);
        const float4 o1 = f4max(f4max(row2, row3), f4max(row4, row5));
        *reinterpret_cast<float4*>(&pooled[(size_t)((((dp0 + 1) * DP + hp) * DP + wp) * 4 + c4) * 4]) = o1;
    }
}

// Gather into (27000, 64, 16); out flat float4 idx == tid, NT store.
__global__ void gather_kernel(const float* __restrict__ pooled, float* __restrict__ out) {
    const int stride = gridDim.x * blockDim.x;
    for (int tid = blockIdx.x * blockDim.x + threadIdx.x; tid < OUT_THREADS; tid += stride) {
        const int c4 = tid & 3;
        const int w = (tid >> 2) & 63;     // (a*4+b)*4+cc
        const int n = tid >> 8;            // patch index (i*30+j)*30+k
        const int cc = w & 3;
        const int b = (w >> 2) & 3;
        const int a = w >> 4;
        const int k = n % NPATCH;
        const int t = n / NPATCH;
        const int j = t % NPATCH;
        const int i = t / NPATCH;
        const int dp = i * 2 + a;
        const int hp = j * 2 + b;
        const int wp = k * 2 + cc;
        const int src = ((dp * DP + hp) * DP + wp) * 4 + c4;  // float4 index
        const f32x4 v = *reinterpret_cast<const f32x4*>(&pooled[(size_t)src * 4]);
        __builtin_nontemporal_store(v, reinterpret_cast<f32x4*>(&out[(size_t)tid * 4]));
    }
}

// Full recompute fallback (no workspace).
__global__ void fused_kernel(const float* __restrict__ x, float* __restrict__ out) {
    const int stride = gridDim.x * blockDim.x;
    for (int tid = blockIdx.x * blockDim.x + threadIdx.x; tid < OUT_THREADS; tid += stride) {
        const int c4 = tid & 3;
        const int w = (tid >> 2) & 63;
        const int n = tid >> 8;
        const int cc = w & 3;
        const int b = (w >> 2) & 3;
        const int a = w >> 4;
        const int k = n % NPATCH;
        const int t = n / NPATCH;
        const int j = t % NPATCH;
        const int i = t / NPATCH;
        const int dp = i * 2 + a;
        const int hp = j * 2 + b;
        const int wp = k * 2 + cc;
        float4 m = make_float4(-INFINITY, -INFINITY, -INFINITY, -INFINITY);
        const int xpos0 = ((dp * 2) * D0 + hp * 2) * D0 + wp * 2;
        for (int u = 0; u < 4; ++u)
            for (int v = 0; v < 4; ++v) {
                const int rowpos = xpos0 + (u * D0 + v) * D0;
#pragma unroll
                for (int ww = 0; ww < 4; ++ww)
                    m = f4max(m, *reinterpret_cast<const float4*>(
                        &x[(size_t)(rowpos + ww) * NC + c4 * 4]));
            }
        *reinterpret_cast<float4*>(&out[(size_t)tid * 4]) = m;
    }
}

extern "C" void kernel_launch(void* const* d_in, const int* in_sizes, int n_in,
                              void* d_out, int out_size, void* d_ws, size_t ws_size,
                              hipStream_t stream) {
    const float* x = (const float*)d_in[0];
    float* out = (float*)d_out;

    const size_t pooled_bytes = (size_t)DP * DP * DP * NC * sizeof(float);  // 16 MB
    const int threads = 256;

    if (ws_size >= pooled_bytes) {
        float* pooled = (float*)d_ws;
        pool_kernel<<<(POOL_THREADS + threads - 1) / threads, threads, 0, stream>>>(x, pooled);

        int blocks = (OUT_THREADS + threads - 1) / threads;
        if (blocks > 2048) blocks = 2048;
        gather_kernel<<<blocks, threads, 0, stream>>>(pooled, out);
    } else {
        int blocks = (OUT_THREADS + threads - 1) / threads;
        if (blocks > 2048) blocks = 2048;
        fused_kernel<<<blocks, threads, 0, stream>>>(x, out);
    }
}

// Round 9
// 92.512 us; speedup vs baseline: 1.0177x; 1.0177x over previous
//
#include <hip/hip_runtime.h>
#include <math.h>

// x: [128,128,128,16] f32 ; MaxPool3d win 4 stride 2 -> pooled [63,63,63,16]
// patches: 30^3 cubes of 4^3 at stride 2 -> out (27000, 64, 16) f32
#define D0 128
#define NC 16
#define DP 63
#define NPATCH 30
#define NSEG 9                       // w-segments: w0 = 14*s, 16 input w each -> 7 wp
#define DCH 2                        // dp outputs per wave-chunk
#define NCHUNK 32                    // ceil(63/2); last chunk emits 1 dp
#define POOL_WAVES (NSEG*DP*NCHUNK)               // wave per (chunk,hp,s)
#define OUT_THREADS  (NPATCH*NPATCH*NPATCH*64*4)  // thread per out float4

typedef float f32x4 __attribute__((ext_vector_type(4)));  // native vec for NT store

__device__ __forceinline__ float4 f4max(float4 a, float4 b) {
    return make_float4(fmaxf(a.x, b.x), fmaxf(a.y, b.y), fmaxf(a.z, b.z), fmaxf(a.w, b.w));
}

__device__ __forceinline__ float4 shfl_down4(float4 v, int d) {
    return make_float4(__shfl_down(v.x, d, 64), __shfl_down(v.y, d, 64),
                       __shfl_down(v.z, d, 64), __shfl_down(v.w, d, 64));
}

// Dense-wave pool: lanes = (c4 fast, wl=lane>>2 -> consecutive INPUT w), so every
// global load is a fully-contiguous 1KB wave transaction. h-pool in registers,
// w-pool (win 4, stride 2) via two lane-shuffles, d-pool over a rolling chunk.
__global__ void pool_kernel(const float* __restrict__ x, float* __restrict__ pooled) {
    const int gw = (blockIdx.x * blockDim.x + threadIdx.x) >> 6;  // global wave id
    if (gw >= POOL_WAVES) return;
    const int lane = threadIdx.x & 63;
    const int c4 = lane & 3;
    const int wl = lane >> 2;            // 0..15, input w offset within segment
    int rest = gw;
    const int s = rest % NSEG; rest /= NSEG;
    const int hp = rest % DP;
    const int chunk = rest / DP;         // 0..31 (wave-uniform)
    const int w = 14 * s + wl;           // input w, <= 14*8+15 = 127
    const int h0 = 2 * hp;
    const int d0r = 4 * chunk;

    float4 rowm[6];
#pragma unroll
    for (int ld = 0; ld < 6; ++ld) {
        const int d = min(d0r + ld, D0 - 1);   // clamp: chunk 31 rows 4,5 unused
        // h-pool: 4 dense 1KB wave loads
        const size_t rbase = ((size_t)d * D0 + h0) * D0 + w;
        float4 hm = *reinterpret_cast<const float4*>(&x[rbase * NC + c4 * 4]);
        hm = f4max(hm, *reinterpret_cast<const float4*>(&x[(rbase + D0) * NC + c4 * 4]));
        hm = f4max(hm, *reinterpret_cast<const float4*>(&x[(rbase + 2 * D0) * NC + c4 * 4]));
        hm = f4max(hm, *reinterpret_cast<const float4*>(&x[(rbase + 3 * D0) * NC + c4 * 4]));
        // w-pool: max over w, w+1, w+2, w+3 (lane+4 = w+1, lane+8 = w+2)
        const float4 m1 = f4max(hm, shfl_down4(hm, 4));
        rowm[ld] = f4max(m1, shfl_down4(m1, 8));
    }

    // emit lanes: even wl <= 12 -> wp = 7*s + wl/2 (each wp covered exactly once)
    const bool emit = ((wl & 1) == 0) && (wl <= 12);
    const int wp = 7 * s + (wl >> 1);
    const int dp0 = 2 * chunk;

    const float4 o0 = f4max(f4max(rowm[0], rowm[1]), f4max(rowm[2], rowm[3]));
    if (emit)
        *reinterpret_cast<float4*>(&pooled[(size_t)(((dp0 * DP + hp) * DP + wp) * 4 + c4) * 4]) = o0;
    if (chunk < NCHUNK - 1) {            // wave-uniform; dp0+1 <= 62
        const float4 o1 = f4max(f4max(rowm[2], rowm[3]), f4max(rowm[4], rowm[5]));
        if (emit)
            *reinterpret_cast<float4*>(&pooled[(size_t)((((dp0 + 1) * DP + hp) * DP + wp) * 4 + c4) * 4]) = o1;
    }
}

// Gather into (27000, 64, 16); out flat float4 idx == tid, NT store.
__global__ void gather_kernel(const float* __restrict__ pooled, float* __restrict__ out) {
    const int stride = gridDim.x * blockDim.x;
    for (int tid = blockIdx.x * blockDim.x + threadIdx.x; tid < OUT_THREADS; tid += stride) {
        const int c4 = tid & 3;
        const int w = (tid >> 2) & 63;     // (a*4+b)*4+cc
        const int n = tid >> 8;            // patch index (i*30+j)*30+k
        const int cc = w & 3;
        const int b = (w >> 2) & 3;
        const int a = w >> 4;
        const int k = n % NPATCH;
        const int t = n / NPATCH;
        const int j = t % NPATCH;
        const int i = t / NPATCH;
        const int dp = i * 2 + a;
        const int hp = j * 2 + b;
        const int wp = k * 2 + cc;
        const int src = ((dp * DP + hp) * DP + wp) * 4 + c4;  // float4 index
        const f32x4 v = *reinterpret_cast<const f32x4*>(&pooled[(size_t)src * 4]);
        __builtin_nontemporal_store(v, reinterpret_cast<f32x4*>(&out[(size_t)tid * 4]));
    }
}

// Full recompute fallback (no workspace).
__global__ void fused_kernel(const float* __restrict__ x, float* __restrict__ out) {
    const int stride = gridDim.x * blockDim.x;
    for (int tid = blockIdx.x * blockDim.x + threadIdx.x; tid < OUT_THREADS; tid += stride) {
        const int c4 = tid & 3;
        const int w = (tid >> 2) & 63;
        const int n = tid >> 8;
        const int cc = w & 3;
        const int b = (w >> 2) & 3;
        const int a = w >> 4;
        const int k = n % NPATCH;
        const int t = n / NPATCH;
        const int j = t % NPATCH;
        const int i = t / NPATCH;
        const int dp = i * 2 + a;
        const int hp = j * 2 + b;
        const int wp = k * 2 + cc;
        float4 m = make_float4(-INFINITY, -INFINITY, -INFINITY, -INFINITY);
        const int xpos0 = ((dp * 2) * D0 + hp * 2) * D0 + wp * 2;
        for (int u = 0; u < 4; ++u)
            for (int v = 0; v < 4; ++v) {
                const int rowpos = xpos0 + (u * D0 + v) * D0;
#pragma unroll
                for (int ww = 0; ww < 4; ++ww)
                    m = f4max(m, *reinterpret_cast<const float4*>(
                        &x[(size_t)(rowpos + ww) * NC + c4 * 4]));
            }
        *reinterpret_cast<float4*>(&out[(size_t)tid * 4]) = m;
    }
}

extern "C" void kernel_launch(void* const* d_in, const int* in_sizes, int n_in,
                              void* d_out, int out_size, void* d_ws, size_t ws_size,
                              hipStream_t stream) {
    const float* x = (const float*)d_in[0];
    float* out = (float*)d_out;

    const size_t pooled_bytes = (size_t)DP * DP * DP * NC * sizeof(float);  // 16 MB
    const int threads = 256;

    if (ws_size >= pooled_bytes) {
        float* pooled = (float*)d_ws;
        const int pool_threads_total = POOL_WAVES * 64;   // 18144 waves
        pool_kernel<<<(pool_threads_total + threads - 1) / threads, threads, 0, stream>>>(x, pooled);

        int blocks = (OUT_THREADS + threads - 1) / threads;
        if (blocks > 2048) blocks = 2048;
        gather_kernel<<<blocks, threads, 0, stream>>>(pooled, out);
    } else {
        int blocks = (OUT_THREADS + threads - 1) / threads;
        if (blocks > 2048) blocks = 2048;
        fused_kernel<<<blocks, threads, 0, stream>>>(x, out);
    }
}

// Round 11
// 87.819 us; speedup vs baseline: 1.0721x; 1.0534x over previous
//
#include <hip/hip_runtime.h>
#include <math.h>

// Fused: x[128,128,128,16] f32 -> MaxPool3d(4, stride 2) -> patches (27000,64,16)
// out[(i*30+j)*30+k][(a*4+b)*4+cc][c] = max over u,v,ww in [0,4) of
//   x[4i+2a+u][4j+2b+v][2(2k+cc)+ww][c]
// Block = (i, j, ks) with ks = k/6 (6 k's per block): 30*30*5 = 4500 blocks.
// Pooled slab needed per block: a in[0,4), b in [0,4), wpl in [0,14) -> 14KB LDS.
#define D0 128
#define NC 16
#define NBLK (30*30*5)

typedef float f32x4 __attribute__((ext_vector_type(4)));

__device__ __forceinline__ float4 f4max(float4 a, float4 b) {
    return make_float4(fmaxf(a.x, b.x), fmaxf(a.y, b.y), fmaxf(a.z, b.z), fmaxf(a.w, b.w));
}
__device__ __forceinline__ float4 shfl_down4(float4 v, int d) {
    return make_float4(__shfl_down(v.x, d, 64), __shfl_down(v.y, d, 64),
                       __shfl_down(v.z, d, 64), __shfl_down(v.w, d, 64));
}

__global__ __launch_bounds__(256) void fused_pool_patch(const float* __restrict__ x,
                                                        float* __restrict__ out) {
    // bijective XCD swizzle (nwg=4500, nwg%8=4): contiguous b-range per XCD
    const int q = NBLK >> 3, r = NBLK & 7;
    const int xcd = blockIdx.x & 7, idx = blockIdx.x >> 3;
    const int b = (xcd < r ? xcd * (q + 1) : r * (q + 1) + (xcd - r) * q) + idx;

    const int i  = b / 150;          // 0..29
    const int rem = b % 150;
    const int j  = rem / 5;          // 0..29
    const int ks = rem % 5;          // 0..4  (k = 6*ks + kl)

    const int wave = threadIdx.x >> 6;   // 0..3
    const int lane = threadIdx.x & 63;
    const int dg = wave & 1;             // d-group: dp_local {0,1} or {2,3}
    const int wh = wave >> 1;            // w-half: wpl 0-6 or 7-13
    const int c4 = lane & 3;             // channel quad
    const int wl = lane >> 2;            // 0..15, consecutive input w

    const int w = 24 * ks + 14 * wh + wl;   // input w, max 125
    const int dbase = 4 * i + 4 * dg;       // d rows dbase..dbase+5, max 125
    const int hbase = 4 * j;                // h rows hbase..hbase+9, max 125

    // acc[dpl][hpl] = max over this wave's (d,h) windows, pre-w-pool (lane = w)
    float4 acc[2][4];
#pragma unroll
    for (int p = 0; p < 2; ++p)
#pragma unroll
        for (int hh = 0; hh < 4; ++hh)
            acc[p][hh] = make_float4(-INFINITY, -INFINITY, -INFINITY, -INFINITY);

#pragma unroll
    for (int dl = 0; dl < 6; ++dl) {           // d = dbase + dl
        const size_t rowb = ((size_t)(dbase + dl) * D0 + hbase) * D0 + w;
        float4 rw[10];
#pragma unroll
        for (int hl = 0; hl < 10; ++hl)        // 10 dense 1KB wave loads
            rw[hl] = *reinterpret_cast<const float4*>(&x[(rowb + hl * D0) * NC + c4 * 4]);
#pragma unroll
        for (int hl = 0; hl < 10; ++hl) {
#pragma unroll
            for (int hpl = 0; hpl < 4; ++hpl) {
                if (hl >= 2 * hpl && hl <= 2 * hpl + 3) {
                    // dpl0 window: dl 0..3 ; dpl1 window: dl 2..5  (static conds)
                    if (dl <= 3) acc[0][hpl] = f4max(acc[0][hpl], rw[hl]);
                    if (dl >= 2) acc[1][hpl] = f4max(acc[1][hpl], rw[hl]);
                }
            }
        }
    }

    // w-pool (win 4, stride 2) via shuffles; stage pooled slab in LDS
    __shared__ float plds[4 * 4 * 14 * 16];     // [a][b][wpl][c] = 14336 B
    const bool emit = ((wl & 1) == 0) && (wl <= 12);
    const int wpl0 = 7 * wh + (wl >> 1);        // 0..13
#pragma unroll
    for (int dpl = 0; dpl < 2; ++dpl) {
#pragma unroll
        for (int hpl = 0; hpl < 4; ++hpl) {
            const float4 v = acc[dpl][hpl];
            const float4 m1 = f4max(v, shfl_down4(v, 4));   // + w+1
            const float4 m2 = f4max(m1, shfl_down4(m1, 8)); // + w+2, w+3
            if (emit) {
                const int a = 2 * dg + dpl;
                *reinterpret_cast<float4*>(
                    &plds[(((a * 4 + hpl) * 14 + wpl0) * 4 + c4) * 4]) = m2;
            }
        }
    }
    __syncthreads();

    // emit 6 patches = 24KB perfectly contiguous, NT stores
    const size_t obase = ((size_t)(i * 30 + j) * 30 + 6 * ks) * 256;  // float4 units
#pragma unroll
    for (int rr = 0; rr < 6; ++rr) {
        const int f = threadIdx.x + 256 * rr;   // 0..1535
        const int kl = f >> 8;                  // 0..5
        const int rowq = (f >> 2) & 63;         // (a*4+b)*4+cc
        const int c4e = f & 3;
        const int a  = rowq >> 4;
        const int bb = (rowq >> 2) & 3;
        const int cc = rowq & 3;
        const int wpl = 2 * kl + cc;            // 0..13
        const f32x4 v = *reinterpret_cast<const f32x4*>(
            &plds[(((a * 4 + bb) * 14 + wpl) * 4 + c4e) * 4]);
        __builtin_nontemporal_store(v, reinterpret_cast<f32x4*>(&out[(obase + f) * 4]));
    }
}

extern "C" void kernel_launch(void* const* d_in, const int* in_sizes, int n_in,
                              void* d_out, int out_size, void* d_ws, size_t ws_size,
                              hipStream_t stream) {
    const float* x = (const float*)d_in[0];
    float* out = (float*)d_out;
    fused_pool_patch<<<NBLK, 256, 0, stream>>>(x, out);
}

// Round 12
// 54.968 us; speedup vs baseline: 1.7128x; 1.5976x over previous
//
#include <hip/hip_runtime.h>
#include <math.h>

// x: [128,128,128,16] f32 ; MaxPool3d win 4 stride 2 -> pooled [63,63,63,16]
// patches: 30^3 cubes of 4^3 at stride 2 -> out (27000, 64, 16) f32
// Phase 1: streaming hw-pool -> hwp[d=128][hp=63][wp=63][c=16]  (32.5 MB in d_ws)
// Phase 2: per-patch-run slab gather: LDS-cache hwp slab, fold d-max, NT-emit.
#define D0 128
#define NC 16
#define DPE 63
#define NP 30
#define NBLK2 (NP*NP*5)    // 4500

typedef float f32x4 __attribute__((ext_vector_type(4)));

__device__ __forceinline__ float4 f4max(float4 a, float4 b) {
    return make_float4(fmaxf(a.x, b.x), fmaxf(a.y, b.y), fmaxf(a.z, b.z), fmaxf(a.w, b.w));
}
__device__ __forceinline__ float4 shfl_down4(float4 v, int d) {
    return make_float4(__shfl_down(v.x, d, 64), __shfl_down(v.y, d, 64),
                       __shfl_down(v.z, d, 64), __shfl_down(v.w, d, 64));
}

// ---------------- Phase 1: dense-streaming hw-pool ----------------
// grid = 256 blocks: (d, hhalf). 576 threads = 9 waves; wave s owns w=14s..14s+15
// (full 8KB row covered with 1.125x overlap -> DRAM sees linear streams).
// h-pool: rolling pair-max (pairs t: rows 2t,2t+1; window hp = pair[hp] v pair[hp+1]).
__global__ __launch_bounds__(576) void hw_pool_stream(const float* __restrict__ x,
                                                      float* __restrict__ hwp) {
    const int bid = blockIdx.x;
    const int d = bid >> 1;
    const int hhalf = bid & 1;
    const int s = threadIdx.x >> 6;      // wave 0..8
    const int lane = threadIdx.x & 63;
    const int wl = lane >> 2;            // 0..15
    const int c4 = lane & 3;
    const int w = 14 * s + wl;           // 0..127

    const int t0 = hhalf ? 32 : 0;       // pair range [t0, t1]
    const int t1 = hhalf ? 63 : 32;      // windows hp = t-1 in [t0, t1-1] -> 0..31 / 32..62

    const float* base = x + ((size_t)d * D0 * D0 + w) * NC + c4 * 4;
    const size_t rowstep = (size_t)D0 * NC;          // 2048 floats per h row

    const bool emit = ((wl & 1) == 0) && (wl <= 12);
    const int wp = 7 * s + (wl >> 1);                // 0..62, each exactly once
    float* outb = hwp + ((size_t)d * DPE * DPE + wp) * NC + c4 * 4;

#define LDROW(h) (*reinterpret_cast<const float4*>(base + (size_t)min(h, D0 - 1) * rowstep))
    // depth-2 row-pair pipeline: ~4KB in flight per wave
    float4 r0 = LDROW(2 * t0),     r1 = LDROW(2 * t0 + 1);
    float4 n0 = LDROW(2 * t0 + 2), n1 = LDROW(2 * t0 + 3);
    float4 prev = make_float4(-INFINITY, -INFINITY, -INFINITY, -INFINITY);

    for (int t = t0; t <= t1; ++t) {
        float4 nn0 = LDROW(2 * t + 4), nn1 = LDROW(2 * t + 5);
        const float4 pair = f4max(r0, r1);
        if (t > t0) {
            const float4 win = f4max(prev, pair);            // rows 2(t-1)..2t+1
            const float4 m1 = f4max(win, shfl_down4(win, 4)); // + w+1
            const float4 m2 = f4max(m1, shfl_down4(m1, 8));   // + w+2, w+3
            if (emit)
                *reinterpret_cast<float4*>(outb + (size_t)(t - 1) * (DPE * NC)) = m2;
        }
        prev = pair;
        r0 = n0; r1 = n1; n0 = nn0; n1 = nn1;
    }
#undef LDROW
}

// ---------------- Phase 2: slab gather with d-fold ----------------
// block = (i, j, ks): slab = hwp[4i..4i+9][2j..2j+3][12ks..12ks+13][:] -> LDS
// (wp padded 14->15 to break bank conflicts), then 6 patches NT-emitted.
__global__ __launch_bounds__(256) void slab_gather(const float* __restrict__ hwp,
                                                   float* __restrict__ out) {
    // bijective XCD swizzle (nwg=4500, nwg%8=4)
    const int q = NBLK2 >> 3, r = NBLK2 & 7;
    const int xcd = blockIdx.x & 7, idx = blockIdx.x >> 3;
    const int b = (xcd < r ? xcd * (q + 1) : r * (q + 1) + (xcd - r) * q) + idx;

    const int i = b / 150;
    const int rem = b % 150;
    const int j = rem / 5;
    const int ks = rem % 5;
    const int tid = threadIdx.x;

    __shared__ float4 slab[10 * 4 * 15 * 4];   // [d_l][hp_l][wp_l pad15][c4] = 38400 B

    // stage 2240 float4s: f -> (d_l, hp_l, wp_l, c4); global runs of 56 f4 = 896B
    for (int it = 0; it < 9; ++it) {
        const int f = tid + 256 * it;
        if (f < 2240) {
            const int d_l = f / 224;           // [10]
            const int r224 = f - d_l * 224;
            const int hp_l = r224 / 56;        // [4]
            const int r56 = r224 - hp_l * 56;
            const int wp_l = r56 >> 2;         // [14]
            const int c4 = f & 3;
            const size_t g = ((size_t)(4 * i + d_l) * DPE + (2 * j + hp_l)) * DPE
                           + (12 * ks + wp_l);
            slab[((d_l * 4 + hp_l) * 15 + wp_l) * 4 + c4] =
                *reinterpret_cast<const float4*>(&hwp[g * NC + c4 * 4]);
        }
    }
    __syncthreads();

    // emit: tid -> (a, b, cc, c4); kl = patch within run
    const int a  = (tid >> 6) & 3;
    const int bb = (tid >> 4) & 3;
    const int cc = (tid >> 2) & 3;
    const int c4 = tid & 3;
    const size_t obase = ((size_t)(i * NP + j) * NP + 6 * ks) * 256;  // float4 units
#pragma unroll
    for (int kl = 0; kl < 6; ++kl) {
        const int wp_l = 2 * kl + cc;
        const int base16 = (((2 * a) * 4 + bb) * 15 + wp_l) * 4 + c4;
        float4 m = slab[base16];                     // d_l = 2a .. 2a+3
        m = f4max(m, slab[base16 + 1 * 240]);        // 240 = 4*15*4 (d_l stride)
        m = f4max(m, slab[base16 + 2 * 240]);
        m = f4max(m, slab[base16 + 3 * 240]);
        const f32x4 v = {m.x, m.y, m.z, m.w};
        __builtin_nontemporal_store(v, reinterpret_cast<f32x4*>(&out[(obase + kl * 256 + tid) * 4]));
    }
}

// ---------------- Fallback: verified round-11 fused kernel (no workspace) ----------------
__global__ __launch_bounds__(256) void fused_pool_patch(const float* __restrict__ x,
                                                        float* __restrict__ out) {
    const int q = NBLK2 >> 3, r = NBLK2 & 7;
    const int xcd = blockIdx.x & 7, idx = blockIdx.x >> 3;
    const int b = (xcd < r ? xcd * (q + 1) : r * (q + 1) + (xcd - r) * q) + idx;
    const int i  = b / 150;
    const int rem = b % 150;
    const int j  = rem / 5;
    const int ks = rem % 5;
    const int wave = threadIdx.x >> 6;
    const int lane = threadIdx.x & 63;
    const int dg = wave & 1;
    const int wh = wave >> 1;
    const int c4 = lane & 3;
    const int wl = lane >> 2;
    const int w = 24 * ks + 14 * wh + wl;
    const int dbase = 4 * i + 4 * dg;
    const int hbase = 4 * j;
    float4 acc[2][4];
#pragma unroll
    for (int p = 0; p < 2; ++p)
#pragma unroll
        for (int hh = 0; hh < 4; ++hh)
            acc[p][hh] = make_float4(-INFINITY, -INFINITY, -INFINITY, -INFINITY);
#pragma unroll
    for (int dl = 0; dl < 6; ++dl) {
        const size_t rowb = ((size_t)(dbase + dl) * D0 + hbase) * D0 + w;
        float4 rw[10];
#pragma unroll
        for (int hl = 0; hl < 10; ++hl)
            rw[hl] = *reinterpret_cast<const float4*>(&x[(rowb + hl * D0) * NC + c4 * 4]);
#pragma unroll
        for (int hl = 0; hl < 10; ++hl) {
#pragma unroll
            for (int hpl = 0; hpl < 4; ++hpl) {
                if (hl >= 2 * hpl && hl <= 2 * hpl + 3) {
                    if (dl <= 3) acc[0][hpl] = f4max(acc[0][hpl], rw[hl]);
                    if (dl >= 2) acc[1][hpl] = f4max(acc[1][hpl], rw[hl]);
                }
            }
        }
    }
    __shared__ float plds[4 * 4 * 14 * 16];
    const bool emit = ((wl & 1) == 0) && (wl <= 12);
    const int wpl0 = 7 * wh + (wl >> 1);
#pragma unroll
    for (int dpl = 0; dpl < 2; ++dpl) {
#pragma unroll
        for (int hpl = 0; hpl < 4; ++hpl) {
            const float4 v = acc[dpl][hpl];
            const float4 m1 = f4max(v, shfl_down4(v, 4));
            const float4 m2 = f4max(m1, shfl_down4(m1, 8));
            if (emit) {
                const int a = 2 * dg + dpl;
                *reinterpret_cast<float4*>(&plds[(((a * 4 + hpl) * 14 + wpl0) * 4 + c4) * 4]) = m2;
            }
        }
    }
    __syncthreads();
    const size_t obase = ((size_t)(i * 30 + j) * 30 + 6 * ks) * 256;
#pragma unroll
    for (int rr = 0; rr < 6; ++rr) {
        const int f = threadIdx.x + 256 * rr;
        const int rowq = (f >> 2) & 63;
        const int c4e = f & 3;
        const int a  = rowq >> 4;
        const int bbq = (rowq >> 2) & 3;
        const int cc = rowq & 3;
        const int wpl = 2 * (f >> 8) + cc;
        const f32x4 v = *reinterpret_cast<const f32x4*>(
            &plds[(((a * 4 + bbq) * 14 + wpl) * 4 + c4e) * 4]);
        __builtin_nontemporal_store(v, reinterpret_cast<f32x4*>(&out[(obase + f) * 4]));
    }
}

extern "C" void kernel_launch(void* const* d_in, const int* in_sizes, int n_in,
                              void* d_out, int out_size, void* d_ws, size_t ws_size,
                              hipStream_t stream) {
    const float* x = (const float*)d_in[0];
    float* out = (float*)d_out;

    const size_t hwp_bytes = (size_t)D0 * DPE * DPE * NC * sizeof(float);  // 32.5 MB
    if (ws_size >= hwp_bytes) {
        float* hwp = (float*)d_ws;
        hw_pool_stream<<<D0 * 2, 576, 0, stream>>>(x, hwp);
        slab_gather<<<NBLK2, 256, 0, stream>>>(hwp, out);
    } else {
        fused_pool_patch<<<NBLK2, 256, 0, stream>>>(x, out);
    }
}

// Round 13
// 50.592 us; speedup vs baseline: 1.8609x; 1.0865x over previous
//
#include <hip/hip_runtime.h>
#include <math.h>

// x: [128,128,128,16] f32 ; MaxPool3d win 4 stride 2 -> pooled [63,63,63,16]
// patches: 30^3 cubes of 4^3 at stride 2 -> out (27000, 64, 16) f32
// Identity: pooled[dp] = max(pair[dp], pair[dp+1]), pair[t] = max(d-rows 2t,2t+1).
// Phase 1: streaming hw-pool + d-PAIR fold -> hwp2[t=63][hp=63][wp=63][c=16] (16 MB)
// Phase 2: per-patch-run slab gather: LDS slab [5][4][14], 2-way d-fold, NT emit.
#define D0 128
#define NC 16
#define DPE 63
#define NP 30
#define NBLK2 (NP*NP*5)    // 4500

typedef float f32x4 __attribute__((ext_vector_type(4)));

__device__ __forceinline__ float4 f4max(float4 a, float4 b) {
    return make_float4(fmaxf(a.x, b.x), fmaxf(a.y, b.y), fmaxf(a.z, b.z), fmaxf(a.w, b.w));
}
__device__ __forceinline__ float4 shfl_down4(float4 v, int d) {
    return make_float4(__shfl_down(v.x, d, 64), __shfl_down(v.y, d, 64),
                       __shfl_down(v.z, d, 64), __shfl_down(v.w, d, 64));
}

// ---------------- Phase 1: dense-streaming hw-pool + d-pair fold ----------------
// grid = (t, hq) = 63*4 = 252 blocks, 576 threads = 9 waves; wave s owns w=14s..14s+15.
// Block streams h-rows of d-slices 2t and 2t+1 (two ~300KB contiguous runs).
__global__ __launch_bounds__(576) void hw_pool_pair(const float* __restrict__ x,
                                                    float* __restrict__ hwp2) {
    const int t = blockIdx.x / 4;        // d-pair index 0..62
    const int hq = blockIdx.x & 3;       // h-quarter
    const int s = threadIdx.x >> 6;      // wave 0..8
    const int lane = threadIdx.x & 63;
    const int wl = lane >> 2;            // 0..15
    const int c4 = lane & 3;
    const int w = 14 * s + wl;           // 0..127

    const int tt0 = 16 * hq;                       // h-pair range [tt0, tt1]
    const int tt1 = min(16 * hq + 16, DPE);        // emit hp = tt-1 in [16hq, ...]

    const size_t rowstep = (size_t)D0 * NC;        // 2048 floats per h row
    const float* base0 = x + ((size_t)(2 * t) * D0 * D0 + w) * NC + c4 * 4;
    const float* base1 = base0 + (size_t)D0 * D0 * NC;

    const bool emit = ((wl & 1) == 0) && (wl <= 12);
    const int wp = 7 * s + (wl >> 1);              // 0..62, each exactly once
    float* outb = hwp2 + ((size_t)t * DPE * DPE + wp) * NC + c4 * 4;

#define LDR(B, h) (*reinterpret_cast<const float4*>((B) + (size_t)min(h, D0 - 1) * rowstep))
    // depth-2 pipeline over h-pairs; each h-pair = 4 rows (2 h x 2 d)
    float4 c0 = LDR(base0, 2 * tt0),     c1 = LDR(base0, 2 * tt0 + 1);
    float4 c2 = LDR(base1, 2 * tt0),     c3 = LDR(base1, 2 * tt0 + 1);
    float4 n0 = LDR(base0, 2 * tt0 + 2), n1 = LDR(base0, 2 * tt0 + 3);
    float4 n2 = LDR(base1, 2 * tt0 + 2), n3 = LDR(base1, 2 * tt0 + 3);
    float4 prev = make_float4(-INFINITY, -INFINITY, -INFINITY, -INFINITY);

    for (int tt = tt0; tt <= tt1; ++tt) {
        float4 m0 = LDR(base0, 2 * tt + 4), m1 = LDR(base0, 2 * tt + 5);
        float4 m2 = LDR(base1, 2 * tt + 4), m3 = LDR(base1, 2 * tt + 5);
        const float4 pair = f4max(f4max(c0, c1), f4max(c2, c3));  // d-pair+h-pair fold
        if (tt > tt0) {
            const float4 win = f4max(prev, pair);              // h rows 2(tt-1)..2tt+1
            const float4 s1 = f4max(win, shfl_down4(win, 4));  // + w+1
            const float4 s2 = f4max(s1, shfl_down4(s1, 8));    // + w+2, w+3
            if (emit)
                *reinterpret_cast<float4*>(outb + (size_t)(tt - 1) * (DPE * NC)) = s2;
        }
        prev = pair;
        c0 = n0; c1 = n1; c2 = n2; c3 = n3;
        n0 = m0; n1 = m1; n2 = m2; n3 = m3;
    }
#undef LDR
}

// ---------------- Phase 2: slab gather with 2-way d-fold ----------------
// block = (i, j, ks): slab = hwp2[2i..2i+4][2j..2j+3][12ks..12ks+13][:] -> LDS
// (wp padded 14->15), pooled[2i+a] = max(slab[a], slab[a+1]); 6 patches NT-emitted.
__global__ __launch_bounds__(256) void slab_gather2(const float* __restrict__ hwp2,
                                                    float* __restrict__ out) {
    // bijective XCD swizzle (nwg=4500, nwg%8=4)
    const int q = NBLK2 >> 3, r = NBLK2 & 7;
    const int xcd = blockIdx.x & 7, idx = blockIdx.x >> 3;
    const int b = (xcd < r ? xcd * (q + 1) : r * (q + 1) + (xcd - r) * q) + idx;

    const int i = b / 150;
    const int rem = b % 150;
    const int j = rem / 5;
    const int ks = rem % 5;
    const int tid = threadIdx.x;

    __shared__ float4 slab[5 * 4 * 15 * 4];   // [t_l][hp_l][wp_l pad15][c4] = 19200 B

    // stage 1120 float4s; global runs of 56 f4 = 896B per (t_l, hp_l)
    for (int it = 0; it < 5; ++it) {
        const int f = tid + 256 * it;
        if (f < 1120) {
            const int t_l = f / 224;           // [5]
            const int r224 = f - t_l * 224;
            const int hp_l = r224 / 56;        // [4]
            const int r56 = r224 - hp_l * 56;
            const int wp_l = r56 >> 2;         // [14]
            const int c4 = f & 3;
            const size_t g = ((size_t)(2 * i + t_l) * DPE + (2 * j + hp_l)) * DPE
                           + (12 * ks + wp_l);
            slab[((t_l * 4 + hp_l) * 15 + wp_l) * 4 + c4] =
                *reinterpret_cast<const float4*>(&hwp2[g * NC + c4 * 4]);
        }
    }
    __syncthreads();

    // emit: tid -> (a, bb, cc, c4); kl = patch within run of 6
    const int a  = (tid >> 6) & 3;
    const int bb = (tid >> 4) & 3;
    const int cc = (tid >> 2) & 3;
    const int c4 = tid & 3;
    const size_t obase = ((size_t)(i * NP + j) * NP + 6 * ks) * 256;  // float4 units
#pragma unroll
    for (int kl = 0; kl < 6; ++kl) {
        const int wp_l = 2 * kl + cc;
        const int base16 = ((a * 4 + bb) * 15 + wp_l) * 4 + c4;
        const float4 m = f4max(slab[base16], slab[base16 + 240]);  // 240 = 4*15*4
        const f32x4 v = {m.x, m.y, m.z, m.w};
        __builtin_nontemporal_store(v, reinterpret_cast<f32x4*>(&out[(obase + kl * 256 + tid) * 4]));
    }
}

// ---------------- Fallback: verified round-11 fused kernel (no workspace) ----------------
__global__ __launch_bounds__(256) void fused_pool_patch(const float* __restrict__ x,
                                                        float* __restrict__ out) {
    const int q = NBLK2 >> 3, r = NBLK2 & 7;
    const int xcd = blockIdx.x & 7, idx = blockIdx.x >> 3;
    const int b = (xcd < r ? xcd * (q + 1) : r * (q + 1) + (xcd - r) * q) + idx;
    const int i  = b / 150;
    const int rem = b % 150;
    const int j  = rem / 5;
    const int ks = rem % 5;
    const int wave = threadIdx.x >> 6;
    const int lane = threadIdx.x & 63;
    const int dg = wave & 1;
    const int wh = wave >> 1;
    const int c4 = lane & 3;
    const int wl = lane >> 2;
    const int w = 24 * ks + 14 * wh + wl;
    const int dbase = 4 * i + 4 * dg;
    const int hbase = 4 * j;
    float4 acc[2][4];
#pragma unroll
    for (int p = 0; p < 2; ++p)
#pragma unroll
        for (int hh = 0; hh < 4; ++hh)
            acc[p][hh] = make_float4(-INFINITY, -INFINITY, -INFINITY, -INFINITY);
#pragma unroll
    for (int dl = 0; dl < 6; ++dl) {
        const size_t rowb = ((size_t)(dbase + dl) * D0 + hbase) * D0 + w;
        float4 rw[10];
#pragma unroll
        for (int hl = 0; hl < 10; ++hl)
            rw[hl] = *reinterpret_cast<const float4*>(&x[(rowb + hl * D0) * NC + c4 * 4]);
#pragma unroll
        for (int hl = 0; hl < 10; ++hl) {
#pragma unroll
            for (int hpl = 0; hpl < 4; ++hpl) {
                if (hl >= 2 * hpl && hl <= 2 * hpl + 3) {
                    if (dl <= 3) acc[0][hpl] = f4max(acc[0][hpl], rw[hl]);
                    if (dl >= 2) acc[1][hpl] = f4max(acc[1][hpl], rw[hl]);
                }
            }
        }
    }
    __shared__ float plds[4 * 4 * 14 * 16];
    const bool emit = ((wl & 1) == 0) && (wl <= 12);
    const int wpl0 = 7 * wh + (wl >> 1);
#pragma unroll
    for (int dpl = 0; dpl < 2; ++dpl) {
#pragma unroll
        for (int hpl = 0; hpl < 4; ++hpl) {
            const float4 v = acc[dpl][hpl];
            const float4 m1 = f4max(v, shfl_down4(v, 4));
            const float4 m2 = f4max(m1, shfl_down4(m1, 8));
            if (emit) {
                const int a = 2 * dg + dpl;
                *reinterpret_cast<float4*>(&plds[(((a * 4 + hpl) * 14 + wpl0) * 4 + c4) * 4]) = m2;
            }
        }
    }
    __syncthreads();
    const size_t obase = ((size_t)(i * 30 + j) * 30 + 6 * ks) * 256;
#pragma unroll
    for (int rr = 0; rr < 6; ++rr) {
        const int f = threadIdx.x + 256 * rr;
        const int rowq = (f >> 2) & 63;
        const int c4e = f & 3;
        const int a  = rowq >> 4;
        const int bbq = (rowq >> 2) & 3;
        const int cc = rowq & 3;
        const int wpl = 2 * (f >> 8) + cc;
        const f32x4 v = *reinterpret_cast<const f32x4*>(
            &plds[(((a * 4 + bbq) * 14 + wpl) * 4 + c4e) * 4]);
        __builtin_nontemporal_store(v, reinterpret_cast<f32x4*>(&out[(obase + f) * 4]));
    }
}

extern "C" void kernel_launch(void* const* d_in, const int* in_sizes, int n_in,
                              void* d_out, int out_size, void* d_ws, size_t ws_size,
                              hipStream_t stream) {
    const float* x = (const float*)d_in[0];
    float* out = (float*)d_out;

    const size_t hwp2_bytes = (size_t)DPE * DPE * DPE * NC * sizeof(float);  // 16 MB
    if (ws_size >= hwp2_bytes) {
        float* hwp2 = (float*)d_ws;
        hw_pool_pair<<<DPE * 4, 576, 0, stream>>>(x, hwp2);
        slab_gather2<<<NBLK2, 256, 0, stream>>>(hwp2, out);
    } else {
        fused_pool_patch<<<NBLK2, 256, 0, stream>>>(x, out);
    }
}